// Round 10
// baseline (805.793 us; speedup 1.0000x reference)
//
#include <hip/hip_runtime.h>
#include <hip/hip_bf16.h>
#include <stdint.h>

typedef unsigned short u16;
typedef __bf16 bf16x8_t __attribute__((ext_vector_type(8)));
typedef float f32x4_t __attribute__((ext_vector_type(4)));
typedef float f32x16_t __attribute__((ext_vector_type(16)));
typedef unsigned int u32x2_t __attribute__((ext_vector_type(2)));

// ---------- helpers ----------
__device__ __forceinline__ u16 f2bf(float f) {
    union { float f; uint32_t u; } c; c.f = f;
    uint32_t r = c.u + 0x7FFFu + ((c.u >> 16) & 1u);
    return (u16)(r >> 16);
}

__device__ __forceinline__ uint32_t pk2(float a, float b) {
    union { __bf16 h[2]; uint32_t u; } z;
    z.h[0] = (__bf16)a; z.h[1] = (__bf16)b;
    return z.u;
}

__device__ __forceinline__ void gld_lds16(const void* g, void* l) {
    __builtin_amdgcn_global_load_lds(
        (__attribute__((address_space(1))) void*)(g),
        (__attribute__((address_space(3))) void*)(l), 16, 0, 0);
}

// Q pre-scale: 1/sqrt(64) * log2(e), so attn uses raw exp2
#define QSCALE 0.18033688011112042f

// ---------- conversions ----------
__global__ void k_convert_x(const float* __restrict__ x, u16* __restrict__ xb) {
    int i = blockIdx.x * 256 + threadIdx.x;           // 2M float4 chunks exactly
    float4 v = ((const float4*)x)[i];
    ushort4 o;
    o.x = f2bf(v.x); o.y = f2bf(v.y); o.z = f2bf(v.z); o.w = f2bf(v.w);
    ((ushort4*)xb)[i] = o;
}

// transpose-convert W[in][out] fp32 -> Wt[out][in] bf16, 4 matrices (q,k,v,o)
__global__ void k_convert_wT(const float* __restrict__ w0, const float* __restrict__ w1,
                             const float* __restrict__ w2, const float* __restrict__ w3,
                             u16* __restrict__ wT) {
    __shared__ u16 t[32][33];
    const float* src = (blockIdx.z == 0) ? w0 : (blockIdx.z == 1) ? w1 : (blockIdx.z == 2) ? w2 : w3;
    u16* dst = wT + (size_t)blockIdx.z * (1024 * 1024);
    int n0 = blockIdx.x * 32, k0 = blockIdx.y * 32;
    int tx = threadIdx.x & 31, ty = threadIdx.x >> 5;  // 32 x 8
    #pragma unroll
    for (int r = 0; r < 4; ++r) {
        int kl = ty * 4 + r;
        t[tx][kl] = f2bf(src[(size_t)(k0 + kl) * 1024 + n0 + tx]);
    }
    __syncthreads();
    #pragma unroll
    for (int r = 0; r < 4; ++r) {
        int nl = ty * 4 + r;
        dst[(size_t)(n0 + nl) * 1024 + k0 + tx] = t[nl][tx];
    }
}

// ---------- GEMM: C[128x128] = A[128xK] * Bt[128xK]^T, K=1024, BK=64, bf16 MFMA ----
template <int MODE>
__global__ __launch_bounds__(256, 2) void k_gemm(
    const u16* __restrict__ A, const u16* __restrict__ WT,
    const float* __restrict__ bias,
    u16* __restrict__ qo, u16* __restrict__ ko, u16* __restrict__ vt,
    float* __restrict__ out) {
    __shared__ u16 lA[128 * 64];   // 16 KB, rows of 8 16B-chunks, chunk j stored at j^(r&7)
    __shared__ u16 lB[128 * 64];
    const int tid = threadIdx.x, wv = tid >> 6, ln = tid & 63;
    const int lo = ln & 15, jg = ln >> 4;
    const int m0 = blockIdx.x * 128;
    int mat, n0;
    if (MODE == 0) { mat = blockIdx.y >> 3; n0 = (blockIdx.y & 7) * 128; }
    else           { mat = 3;               n0 = blockIdx.y * 128; }
    const u16* Bt = WT + (size_t)mat * (1024 * 1024);
    const int wm = wv >> 1, wn = wv & 1;

    f32x4_t acc[4][4];
    #pragma unroll
    for (int i = 0; i < 4; ++i)
        #pragma unroll
        for (int j = 0; j < 4; ++j) acc[i][j] = (f32x4_t){0.f, 0.f, 0.f, 0.f};

    for (int k0 = 0; k0 < 1024; k0 += 64) {
        __syncthreads();
        #pragma unroll
        for (int is = 0; is < 4; ++is) {
            int c = is * 256 + tid;
            int r = c >> 3;
            int j = (c & 7) ^ (r & 7);
            gld_lds16(A  + (size_t)(m0 + r) * 1024 + k0 + j * 8, &lA[(is * 256 + wv * 64) * 8]);
            gld_lds16(Bt + (size_t)(n0 + r) * 1024 + k0 + j * 8, &lB[(is * 256 + wv * 64) * 8]);
        }
        __syncthreads();
        #pragma unroll
        for (int sub = 0; sub < 2; ++sub) {
            bf16x8_t af[4], bfr[4];
            #pragma unroll
            for (int i = 0; i < 4; ++i) {
                int r = wm * 64 + i * 16 + lo;
                af[i] = *(const bf16x8_t*)&lA[(r * 8 + ((sub * 4 + jg) ^ (r & 7))) * 8];
            }
            #pragma unroll
            for (int j = 0; j < 4; ++j) {
                int r = wn * 64 + j * 16 + lo;
                bfr[j] = *(const bf16x8_t*)&lB[(r * 8 + ((sub * 4 + jg) ^ (r & 7))) * 8];
            }
            #pragma unroll
            for (int i = 0; i < 4; ++i)
                #pragma unroll
                for (int j = 0; j < 4; ++j)
                    acc[i][j] = __builtin_amdgcn_mfma_f32_16x16x32_bf16(af[i], bfr[j], acc[i][j], 0, 0, 0);
        }
    }

    if (MODE == 0) {
        if (mat == 2) {
            // V: transposed write vt[bh][d][n], packed ushort4 along n
            #pragma unroll
            for (int j = 0; j < 4; ++j) {
                int col = n0 + wn * 64 + j * 16 + lo;   // h*64+d
                int hh = col >> 6, dd = col & 63;
                #pragma unroll
                for (int i = 0; i < 4; ++i) {
                    int m = m0 + wm * 64 + i * 16 + jg * 4;
                    int bb = m >> 11, nn = m & 2047;
                    ushort4 pkv;
                    pkv.x = f2bf(acc[i][j][0]);
                    pkv.y = f2bf(acc[i][j][1]);
                    pkv.z = f2bf(acc[i][j][2]);
                    pkv.w = f2bf(acc[i][j][3]);
                    *(ushort4*)&vt[(((size_t)(bb * 16 + hh)) * 64 + dd) * 2048 + nn] = pkv;
                }
            }
        } else {
            u16* dst = (mat == 0) ? qo : ko;
            float sc = (mat == 0) ? QSCALE : 1.0f;
            #pragma unroll
            for (int j = 0; j < 4; ++j) {
                int col = n0 + wn * 64 + j * 16 + lo;
                int hh = col >> 6, dd = col & 63;
                #pragma unroll
                for (int i = 0; i < 4; ++i)
                    #pragma unroll
                    for (int rg = 0; rg < 4; ++rg) {
                        int m = m0 + wm * 64 + i * 16 + jg * 4 + rg;
                        int bb = m >> 11, nn = m & 2047;
                        dst[(((size_t)(bb * 16 + hh)) * 2048 + nn) * 64 + dd] = f2bf(acc[i][j][rg] * sc);
                    }
            }
        }
    } else {
        #pragma unroll
        for (int j = 0; j < 4; ++j) {
            int col = n0 + wn * 64 + j * 16 + lo;
            float bv = bias[col];
            #pragma unroll
            for (int i = 0; i < 4; ++i)
                #pragma unroll
                for (int rg = 0; rg < 4; ++rg) {
                    int m = m0 + wm * 64 + i * 16 + jg * 4 + rg;
                    out[(size_t)m * 1024 + col] = acc[i][j][rg] + bv;
                }
        }
    }
}

// ---------- flash attention, de-phased wave groups ----------
// Block: 8 waves x 32 q = 256 q (512 threads). KV tiles of 64. K 3-slot, V 2-slot.
// Group A (wv<4): per step s: QK(s) -> exp(s) -> PV(s)          [MFMA-leading]
// Group B (wv>=4): per step s: exp(s) -> QK(s+1) -> PV(s)       [VALU-leading]
//   (B's z was produced by its QK(s) in step s-1; single z state.)
// SIMD k hosts waves k (A) and k+4 (B): every SIMD always has one VALU-phase
// and one MFMA-phase wave resident -> pipes overlap instead of serializing.
// grid (64 bh, 8 qsplit): bh%8 -> XCD; K/V stay L2-resident per XCD.
// No-max softmax (log2-domain logits via QSCALE); rowsums via mfma(P, ones).
__global__ __launch_bounds__(512, 4) void k_attn(
    const u16* __restrict__ Q, const u16* __restrict__ K,
    const u16* __restrict__ Vg, u16* __restrict__ ctx) {
    __shared__ __align__(16) u16 Kl[3][64 * 64];   // [key][d], chunk j at j^(r&7)
    __shared__ __align__(16) u16 Vl[2][64 * 64];   // [d][kv], chunk j at j^(r&7)

    const int tid = threadIdx.x, wv = tid >> 6, ln = tid & 63;
    const int lq = ln & 31, hi = ln >> 5;
    const int bh = blockIdx.x;
    const int b = bh >> 4, h = bh & 15;
    const size_t base = (size_t)bh * 2048 * 64;    // for Q,K [bh][n][d]
    const u16* Vtg = Vg + (size_t)bh * 64 * 2048;  // vt [bh][d][n]
    const int q0 = blockIdx.y * 256 + wv * 32;

    // Q fragments (B-operand of swapped QK): lane holds Q[q=lq][d=16s+8hi..+7]
    bf16x8_t bQ[4];
    {
        const u16* qp = Q + base + (size_t)(q0 + lq) * 64 + hi * 8;
        #pragma unroll
        for (int s = 0; s < 4; ++s) bQ[s] = *(const bf16x8_t*)(qp + s * 16);
    }
    bf16x8_t ones;
    #pragma unroll
    for (int e = 0; e < 8; ++e) ones[e] = (__bf16)1.0f;
    f32x16_t zro;
    #pragma unroll
    for (int e = 0; e < 16; ++e) zro[e] = 0.f;

    f32x16_t acc[2], lacc;
    #pragma unroll
    for (int e = 0; e < 16; ++e) { acc[0][e] = 0.f; acc[1][e] = 0.f; lacc[e] = 0.f; }

    auto stageK = [&](int slot, int tt) {   // 8 KB tile, 1 gld_lds per thread
        if (tt >= 32) return;
        int r = tid >> 3;
        int j = (tid & 7) ^ (r & 7);
        gld_lds16(K + base + (size_t)(tt * 64 + r) * 64 + j * 8, &Kl[slot][wv * 64 * 8]);
    };
    auto stageV = [&](int slot, int tt) {   // 8 KB tile, 1 gld_lds per thread
        if (tt >= 32) return;
        int r = tid >> 3;                   // d row
        int j = (tid & 7) ^ (r & 7);
        gld_lds16(Vtg + (size_t)r * 2048 + tt * 64 + j * 8, &Vl[slot][wv * 64 * 8]);
    };

    const int swl = lq & 7;

    // QK^T reading K slot ks -> (z0,z1)
    auto QKc = [&](int ks, f32x16_t& z0, f32x16_t& z1) {
        const u16* Kb = &Kl[ks][0];
        {
            const bf16x8_t aK = *(const bf16x8_t*)&Kb[lq * 64 + ((hi ^ swl) * 8)];
            z0 = __builtin_amdgcn_mfma_f32_32x32x16_bf16(aK, bQ[0], zro, 0, 0, 0);
        }
        #pragma unroll
        for (int s = 1; s < 4; ++s) {
            const bf16x8_t aK = *(const bf16x8_t*)&Kb[lq * 64 + (((2 * s + hi) ^ swl) * 8)];
            z0 = __builtin_amdgcn_mfma_f32_32x32x16_bf16(aK, bQ[s], z0, 0, 0, 0);
        }
        {
            const bf16x8_t aK = *(const bf16x8_t*)&Kb[(32 + lq) * 64 + ((hi ^ swl) * 8)];
            z1 = __builtin_amdgcn_mfma_f32_32x32x16_bf16(aK, bQ[0], zro, 0, 0, 0);
        }
        #pragma unroll
        for (int s = 1; s < 4; ++s) {
            const bf16x8_t aK = *(const bf16x8_t*)&Kb[(32 + lq) * 64 + (((2 * s + hi) ^ swl) * 8)];
            z1 = __builtin_amdgcn_mfma_f32_32x32x16_bf16(aK, bQ[s], z1, 0, 0, 0);
        }
    };

    // exp2 + pack both key-halves -> w
    auto EXPall = [&](const f32x16_t& z0, const f32x16_t& z1, uint32_t (&w)[2][4][2]) {
        #pragma unroll
        for (int kg = 0; kg < 2; ++kg) {
            const f32x16_t& z = kg ? z1 : z0;
            #pragma unroll
            for (int m = 0; m < 4; ++m) {
                float p0 = __builtin_amdgcn_exp2f(z[4 * m + 0]);
                float p1 = __builtin_amdgcn_exp2f(z[4 * m + 1]);
                float p2 = __builtin_amdgcn_exp2f(z[4 * m + 2]);
                float p3 = __builtin_amdgcn_exp2f(z[4 * m + 3]);
                w[kg][m][0] = pk2(p0, p1);
                w[kg][m][1] = pk2(p2, p3);
            }
        }
    };

    // PV + rowsum from packed w, reading V slot vs
    auto PVall = [&](int vs, uint32_t (&w)[2][4][2]) {
        const u16* Vb = &Vl[vs][0];
        #pragma unroll
        for (int kg = 0; kg < 2; ++kg) {
            #pragma unroll
            for (int sl = 0; sl < 2; ++sl) {
                const int ma = 2 * sl, sp = 2 * kg + sl;
                u32x2_t r0 = __builtin_amdgcn_permlane32_swap(w[kg][ma][0], w[kg][ma + 1][0], false, false);
                u32x2_t r1 = __builtin_amdgcn_permlane32_swap(w[kg][ma][1], w[kg][ma + 1][1], false, false);
                union { uint32_t u[4]; bf16x8_t v; } ap;
                ap.u[0] = r0[0]; ap.u[1] = r1[0]; ap.u[2] = r0[1]; ap.u[3] = r1[1];
                lacc = __builtin_amdgcn_mfma_f32_32x32x16_bf16(ap.v, ones, lacc, 0, 0, 0);
                #pragma unroll
                for (int dh = 0; dh < 2; ++dh) {
                    const bf16x8_t bV = *(const bf16x8_t*)
                        &Vb[(dh * 32 + lq) * 64 + (((2 * sp + hi) ^ swl) * 8)];
                    acc[dh] = __builtin_amdgcn_mfma_f32_32x32x16_bf16(ap.v, bV, acc[dh], 0, 0, 0);
                }
            }
        }
    };

    // prologue
    stageK(0, 0); stageV(0, 0);
    __syncthreads();                 // K(0), V(0) landed
    stageK(1, 1);                    // K(1) in flight
    f32x16_t zB0, zB1;
    if (wv >= 4) QKc(0, zB0, zB1);   // B pre-computes its z(0) (reads K slot 0)

    int slot_s = 0;                  // K slot holding tile s
    for (int s = 0; s < 32; ++s) {
        __syncthreads();             // K(s+1), V(s) landed; everyone past step s-1
        const int slot_stage = slot_s == 0 ? 2 : slot_s - 1;   // (s+2)%3
        stageK(slot_stage, s + 2);
        stageV((s + 1) & 1, s + 1);
        if (wv < 4) {
            // group A: MFMA-leading
            f32x16_t z0, z1;
            QKc(slot_s, z0, z1);
            uint32_t w[2][4][2];
            EXPall(z0, z1, w);
            PVall(s & 1, w);
        } else {
            // group B: VALU-leading (z from previous step's QK)
            uint32_t w[2][4][2];
            EXPall(zB0, zB1, w);
            if (s < 31) QKc(slot_s == 2 ? 0 : slot_s + 1, zB0, zB1);  // K(s+1)
            PVall(s & 1, w);
        }
        slot_s = slot_s == 2 ? 0 : slot_s + 1;
    }

    // ---- epilogue: elementwise normalize (lacc layout == acc layout), store bf16
    f32x16_t linv;
    #pragma unroll
    for (int e = 0; e < 16; ++e) linv[e] = 1.0f / lacc[e];
    #pragma unroll
    for (int dh = 0; dh < 2; ++dh) {
        int d = dh * 32 + lq;
        #pragma unroll
        for (int e = 0; e < 16; ++e) {
            int q = q0 + (e & 3) + 8 * (e >> 2) + 4 * hi;
            ctx[((size_t)(b * 2048 + q)) * 1024 + h * 64 + d] = f2bf(acc[dh][e] * linv[e]);
        }
    }
}

// ---------- launch ----------
extern "C" void kernel_launch(void* const* d_in, const int* in_sizes, int n_in,
                              void* d_out, int out_size, void* d_ws, size_t ws_size,
                              hipStream_t stream) {
    const float* x  = (const float*)d_in[0];
    const float* Wq = (const float*)d_in[1];
    const float* Wk = (const float*)d_in[2];
    const float* Wv = (const float*)d_in[3];
    const float* Wo = (const float*)d_in[4];
    const float* bo = (const float*)d_in[5];
    float* out = (float*)d_out;

    char* ws = (char*)d_ws;
    u16* xb   = (u16*)(ws);                 // 16 MB  [8192][1024]
    u16* wT   = (u16*)(ws + 16777216);      //  8 MB  [4][1024][1024] (q,k,v,o), [out][in]
    u16* qb   = (u16*)(ws + 25165824);      // 16 MB  [64][2048][64]
    u16* kb   = (u16*)(ws + 41943040);      // 16 MB  [64][2048][64]
    u16* vtb  = (u16*)(ws + 58720256);      // 16 MB  [64][64][2048]  (V transposed)
    u16* ctx  = (u16*)(ws + 75497472);      // 16 MB  [8192][1024]

    k_convert_x<<<8192, 256, 0, stream>>>(x, xb);
    k_convert_wT<<<dim3(32, 32, 4), 256, 0, stream>>>(Wq, Wk, Wv, Wo, wT);
    k_gemm<0><<<dim3(64, 24), 256, 0, stream>>>(xb, wT, nullptr, qb, kb, vtb, nullptr);
    k_attn<<<dim3(64, 8), 512, 0, stream>>>(qb, kb, vtb, ctx);
    k_gemm<1><<<dim3(64, 8), 256, 0, stream>>>(ctx, wT, bo, nullptr, nullptr, nullptr, out);
}

// Round 11
// 224.181 us; speedup vs baseline: 3.5944x; 3.5944x over previous
//
#include <hip/hip_runtime.h>
#include <hip/hip_bf16.h>
#include <stdint.h>

typedef unsigned short u16;
typedef __bf16 bf16x8_t __attribute__((ext_vector_type(8)));
typedef float f32x4_t __attribute__((ext_vector_type(4)));
typedef float f32x16_t __attribute__((ext_vector_type(16)));
typedef unsigned int u32x2_t __attribute__((ext_vector_type(2)));

// ---------- helpers ----------
__device__ __forceinline__ u16 f2bf(float f) {
    union { float f; uint32_t u; } c; c.f = f;
    uint32_t r = c.u + 0x7FFFu + ((c.u >> 16) & 1u);
    return (u16)(r >> 16);
}

__device__ __forceinline__ uint32_t pk2(float a, float b) {
    union { __bf16 h[2]; uint32_t u; } z;
    z.h[0] = (__bf16)a; z.h[1] = (__bf16)b;
    return z.u;
}

__device__ __forceinline__ void gld_lds16(const void* g, void* l) {
    __builtin_amdgcn_global_load_lds(
        (__attribute__((address_space(1))) void*)(g),
        (__attribute__((address_space(3))) void*)(l), 16, 0, 0);
}

// Q pre-scale: 1/sqrt(64) * log2(e), so attn uses raw exp2
#define QSCALE 0.18033688011112042f

// ---------- conversions ----------
__global__ void k_convert_x(const float* __restrict__ x, u16* __restrict__ xb) {
    int i = blockIdx.x * 256 + threadIdx.x;           // 2M float4 chunks exactly
    float4 v = ((const float4*)x)[i];
    ushort4 o;
    o.x = f2bf(v.x); o.y = f2bf(v.y); o.z = f2bf(v.z); o.w = f2bf(v.w);
    ((ushort4*)xb)[i] = o;
}

// transpose-convert W[in][out] fp32 -> Wt[out][in] bf16, 4 matrices (q,k,v,o)
__global__ void k_convert_wT(const float* __restrict__ w0, const float* __restrict__ w1,
                             const float* __restrict__ w2, const float* __restrict__ w3,
                             u16* __restrict__ wT) {
    __shared__ u16 t[32][33];
    const float* src = (blockIdx.z == 0) ? w0 : (blockIdx.z == 1) ? w1 : (blockIdx.z == 2) ? w2 : w3;
    u16* dst = wT + (size_t)blockIdx.z * (1024 * 1024);
    int n0 = blockIdx.x * 32, k0 = blockIdx.y * 32;
    int tx = threadIdx.x & 31, ty = threadIdx.x >> 5;  // 32 x 8
    #pragma unroll
    for (int r = 0; r < 4; ++r) {
        int kl = ty * 4 + r;
        t[tx][kl] = f2bf(src[(size_t)(k0 + kl) * 1024 + n0 + tx]);
    }
    __syncthreads();
    #pragma unroll
    for (int r = 0; r < 4; ++r) {
        int nl = ty * 4 + r;
        dst[(size_t)(n0 + nl) * 1024 + k0 + tx] = t[nl][tx];
    }
}

// ---------- GEMM: C[128x128] = A[128xK] * Bt[128xK]^T, K=1024, BK=64, bf16 MFMA ----
// MODE 0: A=xb, Bt=Wq/Wk/Wv^T; q scaled by QSCALE -> qo[bh][n][d];
//         k -> ko[bh][n][d]; v -> TRANSPOSED vt[bh][d][n] (ushort4 along n).
// MODE 1: A=ctx, Bt=Wo^T, write out fp32 + bias
template <int MODE>
__global__ __launch_bounds__(256, 2) void k_gemm(
    const u16* __restrict__ A, const u16* __restrict__ WT,
    const float* __restrict__ bias,
    u16* __restrict__ qo, u16* __restrict__ ko, u16* __restrict__ vt,
    float* __restrict__ out) {
    __shared__ u16 lA[128 * 64];   // 16 KB, rows of 8 16B-chunks, chunk j stored at j^(r&7)
    __shared__ u16 lB[128 * 64];
    const int tid = threadIdx.x, wv = tid >> 6, ln = tid & 63;
    const int lo = ln & 15, jg = ln >> 4;
    const int m0 = blockIdx.x * 128;
    int mat, n0;
    if (MODE == 0) { mat = blockIdx.y >> 3; n0 = (blockIdx.y & 7) * 128; }
    else           { mat = 3;               n0 = blockIdx.y * 128; }
    const u16* Bt = WT + (size_t)mat * (1024 * 1024);
    const int wm = wv >> 1, wn = wv & 1;

    f32x4_t acc[4][4];
    #pragma unroll
    for (int i = 0; i < 4; ++i)
        #pragma unroll
        for (int j = 0; j < 4; ++j) acc[i][j] = (f32x4_t){0.f, 0.f, 0.f, 0.f};

    for (int k0 = 0; k0 < 1024; k0 += 64) {
        __syncthreads();
        #pragma unroll
        for (int is = 0; is < 4; ++is) {
            int c = is * 256 + tid;
            int r = c >> 3;
            int j = (c & 7) ^ (r & 7);
            gld_lds16(A  + (size_t)(m0 + r) * 1024 + k0 + j * 8, &lA[(is * 256 + wv * 64) * 8]);
            gld_lds16(Bt + (size_t)(n0 + r) * 1024 + k0 + j * 8, &lB[(is * 256 + wv * 64) * 8]);
        }
        __syncthreads();
        #pragma unroll
        for (int sub = 0; sub < 2; ++sub) {
            bf16x8_t af[4], bfr[4];
            #pragma unroll
            for (int i = 0; i < 4; ++i) {
                int r = wm * 64 + i * 16 + lo;
                af[i] = *(const bf16x8_t*)&lA[(r * 8 + ((sub * 4 + jg) ^ (r & 7))) * 8];
            }
            #pragma unroll
            for (int j = 0; j < 4; ++j) {
                int r = wn * 64 + j * 16 + lo;
                bfr[j] = *(const bf16x8_t*)&lB[(r * 8 + ((sub * 4 + jg) ^ (r & 7))) * 8];
            }
            #pragma unroll
            for (int i = 0; i < 4; ++i)
                #pragma unroll
                for (int j = 0; j < 4; ++j)
                    acc[i][j] = __builtin_amdgcn_mfma_f32_16x16x32_bf16(af[i], bfr[j], acc[i][j], 0, 0, 0);
        }
    }

    if (MODE == 0) {
        if (mat == 2) {
            // V: transposed write vt[bh][d][n], packed ushort4 along n
            #pragma unroll
            for (int j = 0; j < 4; ++j) {
                int col = n0 + wn * 64 + j * 16 + lo;   // h*64+d
                int hh = col >> 6, dd = col & 63;
                #pragma unroll
                for (int i = 0; i < 4; ++i) {
                    int m = m0 + wm * 64 + i * 16 + jg * 4;
                    int bb = m >> 11, nn = m & 2047;
                    ushort4 pkv;
                    pkv.x = f2bf(acc[i][j][0]);
                    pkv.y = f2bf(acc[i][j][1]);
                    pkv.z = f2bf(acc[i][j][2]);
                    pkv.w = f2bf(acc[i][j][3]);
                    *(ushort4*)&vt[(((size_t)(bb * 16 + hh)) * 64 + dd) * 2048 + nn] = pkv;
                }
            }
        } else {
            u16* dst = (mat == 0) ? qo : ko;
            float sc = (mat == 0) ? QSCALE : 1.0f;
            #pragma unroll
            for (int j = 0; j < 4; ++j) {
                int col = n0 + wn * 64 + j * 16 + lo;
                int hh = col >> 6, dd = col & 63;
                #pragma unroll
                for (int i = 0; i < 4; ++i)
                    #pragma unroll
                    for (int rg = 0; rg < 4; ++rg) {
                        int m = m0 + wm * 64 + i * 16 + jg * 4 + rg;
                        int bb = m >> 11, nn = m & 2047;
                        dst[(((size_t)(bb * 16 + hh)) * 2048 + nn) * 64 + dd] = f2bf(acc[i][j][rg] * sc);
                    }
            }
        }
    } else {
        #pragma unroll
        for (int j = 0; j < 4; ++j) {
            int col = n0 + wn * 64 + j * 16 + lo;
            float bv = bias[col];
            #pragma unroll
            for (int i = 0; i < 4; ++i)
                #pragma unroll
                for (int rg = 0; rg < 4; ++rg) {
                    int m = m0 + wm * 64 + i * 16 + jg * 4 + rg;
                    out[(size_t)m * 1024 + col] = acc[i][j][rg] + bv;
                }
        }
    }
}

// ---------- flash attention, 32x32 MFMA, swapped QK^T, in-register P ----------
// Block: 8 waves x 32 q-rows = 256 q (512 threads). KV tiles of 64, double-buffered
// K/Vt in LDS, both staged lane-linear via gld_lds16 (V pre-transposed in HBM).
// grid = (64 bh, 8 qsplit): dispatch-id % 8 == bh % 8 -> all q-blocks of one
// (b,h) land on one XCD, K/V stay L2-resident per XCD.
// No-max softmax (logits pre-scaled to log2 domain via QSCALE).
// Row-sums are LANE-LOCAL in the swapped layout (lane lq holds P for q=lq over
// 16 keys): scalar fp32 accumulation per tile, one permlane32_swap + LDS
// redistribute at the epilogue. (Replaces the former rowsum-mfma: -20% MFMA issue.)
__global__ __launch_bounds__(512, 4) void k_attn(
    const u16* __restrict__ Q, const u16* __restrict__ K,
    const u16* __restrict__ Vg, u16* __restrict__ ctx) {
    __shared__ __align__(16) u16 Kl[2][64 * 64];   // [key][d], XOR-swizzled 16B chunks
    __shared__ __align__(16) u16 Vt[2][64 * 64];   // [d][kv], XOR-swizzled 16B chunks
    __shared__ float lred[8][32];                  // per-wave 1/l, indexed by q

    const int tid = threadIdx.x, wv = tid >> 6, ln = tid & 63;
    const int lq = ln & 31, hi = ln >> 5;
    const int bh = blockIdx.x;
    const int b = bh >> 4, h = bh & 15;
    const size_t base = (size_t)bh * 2048 * 64;    // for Q,K [bh][n][d]
    const u16* Vtg = Vg + (size_t)bh * 64 * 2048;  // vt [bh][d][n]
    const int q0 = blockIdx.y * 256 + wv * 32;

    // Q fragments (B-operand of swapped QK): lane holds Q[q=lq][d=16s+8hi..+7]
    bf16x8_t bQ[4];
    {
        const u16* qp = Q + base + (size_t)(q0 + lq) * 64 + hi * 8;
        #pragma unroll
        for (int s = 0; s < 4; ++s) bQ[s] = *(const bf16x8_t*)(qp + s * 16);
    }
    f32x16_t zro;
    #pragma unroll
    for (int e = 0; e < 16; ++e) zro[e] = 0.f;

    f32x16_t acc[2];
    #pragma unroll
    for (int e = 0; e < 16; ++e) { acc[0][e] = 0.f; acc[1][e] = 0.f; }
    float lsum = 0.f;

    auto stageK = [&](int buf, int kv0) {
        int r = tid >> 3;
        int j = (tid & 7) ^ (r & 7);
        gld_lds16(K + base + (size_t)(kv0 + r) * 64 + j * 8, &Kl[buf][wv * 64 * 8]);
    };
    auto stageV = [&](int buf, int kv0) {
        int r = tid >> 3;                      // r = d row of vt tile
        int j = (tid & 7) ^ (r & 7);
        gld_lds16(Vtg + (size_t)r * 2048 + kv0 + j * 8, &Vt[buf][wv * 64 * 8]);
    };

    const int swl = lq & 7;

    auto compute = [&](int c) {
        // QK^T both 32-key halves first (8 independent-chain MFMAs)
        f32x16_t z0, z1;
        {
            const bf16x8_t aK = *(const bf16x8_t*)&Kl[c][lq * 64 + ((hi ^ swl) * 8)];
            z0 = __builtin_amdgcn_mfma_f32_32x32x16_bf16(aK, bQ[0], zro, 0, 0, 0);
        }
        #pragma unroll
        for (int s = 1; s < 4; ++s) {
            const bf16x8_t aK = *(const bf16x8_t*)
                &Kl[c][lq * 64 + (((2 * s + hi) ^ swl) * 8)];
            z0 = __builtin_amdgcn_mfma_f32_32x32x16_bf16(aK, bQ[s], z0, 0, 0, 0);
        }
        {
            const bf16x8_t aK = *(const bf16x8_t*)&Kl[c][(32 + lq) * 64 + ((hi ^ swl) * 8)];
            z1 = __builtin_amdgcn_mfma_f32_32x32x16_bf16(aK, bQ[0], zro, 0, 0, 0);
        }
        #pragma unroll
        for (int s = 1; s < 4; ++s) {
            const bf16x8_t aK = *(const bf16x8_t*)
                &Kl[c][(32 + lq) * 64 + (((2 * s + hi) ^ swl) * 8)];
            z1 = __builtin_amdgcn_mfma_f32_32x32x16_bf16(aK, bQ[s], z1, 0, 0, 0);
        }
        // kg halves: exp/pack (+scalar rowsum) then PV; exp1 can overlap PV0
        #pragma unroll
        for (int kg = 0; kg < 2; ++kg) {
            const f32x16_t& z = kg ? z1 : z0;
            uint32_t w[4][2];
            float rs = 0.f;
            #pragma unroll
            for (int m = 0; m < 4; ++m) {
                float p0 = __builtin_amdgcn_exp2f(z[4 * m + 0]);
                float p1 = __builtin_amdgcn_exp2f(z[4 * m + 1]);
                float p2 = __builtin_amdgcn_exp2f(z[4 * m + 2]);
                float p3 = __builtin_amdgcn_exp2f(z[4 * m + 3]);
                rs += (p0 + p1) + (p2 + p3);
                w[m][0] = pk2(p0, p1);
                w[m][1] = pk2(p2, p3);
            }
            lsum += rs;
            #pragma unroll
            for (int sl = 0; sl < 2; ++sl) {
                const int ma = 2 * sl, sp = 2 * kg + sl;
                u32x2_t r0 = __builtin_amdgcn_permlane32_swap(w[ma][0], w[ma + 1][0], false, false);
                u32x2_t r1 = __builtin_amdgcn_permlane32_swap(w[ma][1], w[ma + 1][1], false, false);
                union { uint32_t u[4]; bf16x8_t v; } ap;
                ap.u[0] = r0[0]; ap.u[1] = r1[0]; ap.u[2] = r0[1]; ap.u[3] = r1[1];
                #pragma unroll
                for (int dh = 0; dh < 2; ++dh) {
                    const bf16x8_t bV = *(const bf16x8_t*)
                        &Vt[c][(dh * 32 + lq) * 64 + (((2 * sp + hi) ^ swl) * 8)];
                    acc[dh] = __builtin_amdgcn_mfma_f32_32x32x16_bf16(ap.v, bV, acc[dh], 0, 0, 0);
                }
            }
        }
    };

    // prologue: stage tile 0
    stageK(0, 0);
    stageV(0, 0);
    __syncthreads();    // drains gld_lds (vmcnt) before reads

    for (int i = 0; i < 16; ++i) {
        const int t = 2 * i;
        stageK(1, (t + 1) * 64);           // T14: issue next-tile loads early
        stageV(1, (t + 1) * 64);
        compute(0);
        __syncthreads();
        if (t + 2 < 32) {
            stageK(0, (t + 2) * 64);
            stageV(0, (t + 2) * 64);
        }
        compute(1);
        __syncthreads();
    }

    // ---- epilogue: combine hi-halves of lsum (same q, disjoint keys), build 1/l
    {
        uint32_t lx = __builtin_bit_cast(uint32_t, lsum);
        u32x2_t r = __builtin_amdgcn_permlane32_swap(lx, lx, false, false);
        float partner = __builtin_bit_cast(float, hi ? r[0] : r[1]);
        float tot = lsum + partner;
        if (hi == 0) lred[wv][lq] = 1.0f / tot;   // per-q inverse sum
    }
    __syncthreads();
    // acc rows hold q = (e&3)+8*(e>>2)+4*hi -> gather 1/l in f32x4 groups
    f32x4_t linv[4];
    #pragma unroll
    for (int g = 0; g < 4; ++g)
        linv[g] = *(const f32x4_t*)&lred[wv][g * 8 + 4 * hi];
    #pragma unroll
    for (int dh = 0; dh < 2; ++dh) {
        int d = dh * 32 + lq;
        #pragma unroll
        for (int e = 0; e < 16; ++e) {
            int q = q0 + (e & 3) + 8 * (e >> 2) + 4 * hi;
            ctx[((size_t)(b * 2048 + q)) * 1024 + h * 64 + d] =
                f2bf(acc[dh][e] * linv[e >> 2][e & 3]);
        }
    }
}

// ---------- launch ----------
extern "C" void kernel_launch(void* const* d_in, const int* in_sizes, int n_in,
                              void* d_out, int out_size, void* d_ws, size_t ws_size,
                              hipStream_t stream) {
    const float* x  = (const float*)d_in[0];
    const float* Wq = (const float*)d_in[1];
    const float* Wk = (const float*)d_in[2];
    const float* Wv = (const float*)d_in[3];
    const float* Wo = (const float*)d_in[4];
    const float* bo = (const float*)d_in[5];
    float* out = (float*)d_out;

    char* ws = (char*)d_ws;
    u16* xb   = (u16*)(ws);                 // 16 MB  [8192][1024]
    u16* wT   = (u16*)(ws + 16777216);      //  8 MB  [4][1024][1024] (q,k,v,o), [out][in]
    u16* qb   = (u16*)(ws + 25165824);      // 16 MB  [64][2048][64]
    u16* kb   = (u16*)(ws + 41943040);      // 16 MB  [64][2048][64]
    u16* vtb  = (u16*)(ws + 58720256);      // 16 MB  [64][64][2048]  (V transposed)
    u16* ctx  = (u16*)(ws + 75497472);      // 16 MB  [8192][1024]

    k_convert_x<<<8192, 256, 0, stream>>>(x, xb);
    k_convert_wT<<<dim3(32, 32, 4), 256, 0, stream>>>(Wq, Wk, Wv, Wo, wT);
    k_gemm<0><<<dim3(64, 24), 256, 0, stream>>>(xb, wT, nullptr, qb, kb, vtb, nullptr);
    k_attn<<<dim3(64, 8), 512, 0, stream>>>(qb, kb, vtb, ctx);
    k_gemm<1><<<dim3(64, 8), 256, 0, stream>>>(ctx, wT, bo, nullptr, nullptr, nullptr, out);
}

// Round 12
// 191.155 us; speedup vs baseline: 4.2154x; 1.1728x over previous
//
#include <hip/hip_runtime.h>
#include <hip/hip_bf16.h>
#include <stdint.h>

typedef unsigned short u16;
typedef __bf16 bf16x8_t __attribute__((ext_vector_type(8)));
typedef float f32x4_t __attribute__((ext_vector_type(4)));
typedef float f32x16_t __attribute__((ext_vector_type(16)));
typedef unsigned int u32x2_t __attribute__((ext_vector_type(2)));

// ---------- helpers ----------
__device__ __forceinline__ u16 f2bf(float f) {
    union { float f; uint32_t u; } c; c.f = f;
    uint32_t r = c.u + 0x7FFFu + ((c.u >> 16) & 1u);
    return (u16)(r >> 16);
}

__device__ __forceinline__ uint32_t pk2(float a, float b) {
    union { __bf16 h[2]; uint32_t u; } z;
    z.h[0] = (__bf16)a; z.h[1] = (__bf16)b;
    return z.u;
}

__device__ __forceinline__ void gld_lds16(const void* g, void* l) {
    __builtin_amdgcn_global_load_lds(
        (__attribute__((address_space(1))) void*)(g),
        (__attribute__((address_space(3))) void*)(l), 16, 0, 0);
}

// Q pre-scale: 1/sqrt(64) * log2(e), so attn uses raw exp2
#define QSCALE 0.18033688011112042f

// ---------- conversions ----------
__global__ void k_convert_x(const float* __restrict__ x, u16* __restrict__ xb) {
    int i = blockIdx.x * 256 + threadIdx.x;           // 2M float4 chunks exactly
    float4 v = ((const float4*)x)[i];
    ushort4 o;
    o.x = f2bf(v.x); o.y = f2bf(v.y); o.z = f2bf(v.z); o.w = f2bf(v.w);
    ((ushort4*)xb)[i] = o;
}

// transpose-convert W[in][out] fp32 -> Wt[out][in] bf16, 4 matrices (q,k,v,o)
__global__ void k_convert_wT(const float* __restrict__ w0, const float* __restrict__ w1,
                             const float* __restrict__ w2, const float* __restrict__ w3,
                             u16* __restrict__ wT) {
    __shared__ u16 t[32][33];
    const float* src = (blockIdx.z == 0) ? w0 : (blockIdx.z == 1) ? w1 : (blockIdx.z == 2) ? w2 : w3;
    u16* dst = wT + (size_t)blockIdx.z * (1024 * 1024);
    int n0 = blockIdx.x * 32, k0 = blockIdx.y * 32;
    int tx = threadIdx.x & 31, ty = threadIdx.x >> 5;  // 32 x 8
    #pragma unroll
    for (int r = 0; r < 4; ++r) {
        int kl = ty * 4 + r;
        t[tx][kl] = f2bf(src[(size_t)(k0 + kl) * 1024 + n0 + tx]);
    }
    __syncthreads();
    #pragma unroll
    for (int r = 0; r < 4; ++r) {
        int nl = ty * 4 + r;
        dst[(size_t)(n0 + nl) * 1024 + k0 + tx] = t[nl][tx];
    }
}

// ---------- GEMM: C[128x128] = A[128xK] * Bt[128xK]^T, K=1024, BK=64, bf16 MFMA ----
// 2-PHASE double-buffered staging (T3-min): stage(next) issued BEFORE compute(cur),
// one barrier per K-step; per-wave gld_lds drain at its own barrier guarantees
// the prefetched tile has landed before the next compute.
// MODE 0: A=xb, Bt=Wq/Wk/Wv^T; q scaled by QSCALE -> qo[bh][n][d];
//         k -> ko[bh][n][d]; v -> TRANSPOSED vt[bh][d][n] (ushort4 along n).
// MODE 1: A=ctx, Bt=Wo^T, write out fp32 + bias
template <int MODE>
__global__ __launch_bounds__(256, 2) void k_gemm(
    const u16* __restrict__ A, const u16* __restrict__ WT,
    const float* __restrict__ bias,
    u16* __restrict__ qo, u16* __restrict__ ko, u16* __restrict__ vt,
    float* __restrict__ out) {
    __shared__ u16 lA[2][128 * 64];   // 2 x 16 KB, chunk j stored at j^(r&7)
    __shared__ u16 lB[2][128 * 64];
    const int tid = threadIdx.x, wv = tid >> 6, ln = tid & 63;
    const int lo = ln & 15, jg = ln >> 4;
    const int m0 = blockIdx.x * 128;
    int mat, n0;
    if (MODE == 0) { mat = blockIdx.y >> 3; n0 = (blockIdx.y & 7) * 128; }
    else           { mat = 3;               n0 = blockIdx.y * 128; }
    const u16* Bt = WT + (size_t)mat * (1024 * 1024);
    const int wm = wv >> 1, wn = wv & 1;

    f32x4_t acc[4][4];
    #pragma unroll
    for (int i = 0; i < 4; ++i)
        #pragma unroll
        for (int j = 0; j < 4; ++j) acc[i][j] = (f32x4_t){0.f, 0.f, 0.f, 0.f};

    auto stage = [&](int buf, int k0) {
        #pragma unroll
        for (int is = 0; is < 4; ++is) {
            int c = is * 256 + tid;
            int r = c >> 3;
            int j = (c & 7) ^ (r & 7);
            gld_lds16(A  + (size_t)(m0 + r) * 1024 + k0 + j * 8, &lA[buf][(is * 256 + wv * 64) * 8]);
            gld_lds16(Bt + (size_t)(n0 + r) * 1024 + k0 + j * 8, &lB[buf][(is * 256 + wv * 64) * 8]);
        }
    };
    auto computeG = [&](int buf) {
        #pragma unroll
        for (int sub = 0; sub < 2; ++sub) {
            bf16x8_t af[4], bfr[4];
            #pragma unroll
            for (int i = 0; i < 4; ++i) {
                int r = wm * 64 + i * 16 + lo;
                af[i] = *(const bf16x8_t*)&lA[buf][(r * 8 + ((sub * 4 + jg) ^ (r & 7))) * 8];
            }
            #pragma unroll
            for (int j = 0; j < 4; ++j) {
                int r = wn * 64 + j * 16 + lo;
                bfr[j] = *(const bf16x8_t*)&lB[buf][(r * 8 + ((sub * 4 + jg) ^ (r & 7))) * 8];
            }
            #pragma unroll
            for (int i = 0; i < 4; ++i)
                #pragma unroll
                for (int j = 0; j < 4; ++j)
                    acc[i][j] = __builtin_amdgcn_mfma_f32_16x16x32_bf16(af[i], bfr[j], acc[i][j], 0, 0, 0);
        }
    };

    stage(0, 0);
    __syncthreads();                     // tile 0 landed
    for (int i2 = 0; i2 < 8; ++i2) {
        const int kt = 2 * i2;
        stage(1, (kt + 1) * 64);         // prefetch next while computing cur
        computeG(0);
        __syncthreads();                 // tile kt+1 landed; buf0 free
        if (kt + 2 < 16) stage(0, (kt + 2) * 64);
        computeG(1);
        __syncthreads();                 // tile kt+2 landed; buf1 free
    }

    if (MODE == 0) {
        if (mat == 2) {
            // V: transposed write vt[bh][d][n], packed ushort4 along n
            #pragma unroll
            for (int j = 0; j < 4; ++j) {
                int col = n0 + wn * 64 + j * 16 + lo;   // h*64+d
                int hh = col >> 6, dd = col & 63;
                #pragma unroll
                for (int i = 0; i < 4; ++i) {
                    int m = m0 + wm * 64 + i * 16 + jg * 4;
                    int bb = m >> 11, nn = m & 2047;
                    ushort4 pkv;
                    pkv.x = f2bf(acc[i][j][0]);
                    pkv.y = f2bf(acc[i][j][1]);
                    pkv.z = f2bf(acc[i][j][2]);
                    pkv.w = f2bf(acc[i][j][3]);
                    *(ushort4*)&vt[(((size_t)(bb * 16 + hh)) * 64 + dd) * 2048 + nn] = pkv;
                }
            }
        } else {
            u16* dst = (mat == 0) ? qo : ko;
            float sc = (mat == 0) ? QSCALE : 1.0f;
            #pragma unroll
            for (int j = 0; j < 4; ++j) {
                int col = n0 + wn * 64 + j * 16 + lo;
                int hh = col >> 6, dd = col & 63;
                #pragma unroll
                for (int i = 0; i < 4; ++i)
                    #pragma unroll
                    for (int rg = 0; rg < 4; ++rg) {
                        int m = m0 + wm * 64 + i * 16 + jg * 4 + rg;
                        int bb = m >> 11, nn = m & 2047;
                        dst[(((size_t)(bb * 16 + hh)) * 2048 + nn) * 64 + dd] = f2bf(acc[i][j][rg] * sc);
                    }
            }
        }
    } else {
        #pragma unroll
        for (int j = 0; j < 4; ++j) {
            int col = n0 + wn * 64 + j * 16 + lo;
            float bv = bias[col];
            #pragma unroll
            for (int i = 0; i < 4; ++i)
                #pragma unroll
                for (int rg = 0; rg < 4; ++rg) {
                    int m = m0 + wm * 64 + i * 16 + jg * 4 + rg;
                    out[(size_t)m * 1024 + col] = acc[i][j][rg] + bv;
                }
        }
    }
}

// ---------- flash attention, 32x32 MFMA, swapped QK^T, in-register P ----------
// (exact R6 kernel — verified 85.5 us) Block: 8 waves x 32 q = 256 q (512 thr).
// KV tiles of 64, double-buffered K/Vt in LDS via gld_lds16 (V pre-transposed).
// grid (64 bh, 8 qsplit): bh%8 -> XCD. No-max softmax (log2 domain via QSCALE).
// Row-sums via mfma(P, ones): lacc has the SAME lane layout as acc.
__global__ __launch_bounds__(512, 4) void k_attn(
    const u16* __restrict__ Q, const u16* __restrict__ K,
    const u16* __restrict__ Vg, u16* __restrict__ ctx) {
    __shared__ __align__(16) u16 Kl[2][64 * 64];   // [key][d], XOR-swizzled 16B chunks
    __shared__ __align__(16) u16 Vt[2][64 * 64];   // [d][kv], XOR-swizzled 16B chunks

    const int tid = threadIdx.x, wv = tid >> 6, ln = tid & 63;
    const int lq = ln & 31, hi = ln >> 5;
    const int bh = blockIdx.x;
    const int b = bh >> 4, h = bh & 15;
    const size_t base = (size_t)bh * 2048 * 64;    // for Q,K [bh][n][d]
    const u16* Vtg = Vg + (size_t)bh * 64 * 2048;  // vt [bh][d][n]
    const int q0 = blockIdx.y * 256 + wv * 32;

    // Q fragments (B-operand of swapped QK): lane holds Q[q=lq][d=16s+8hi..+7]
    bf16x8_t bQ[4];
    {
        const u16* qp = Q + base + (size_t)(q0 + lq) * 64 + hi * 8;
        #pragma unroll
        for (int s = 0; s < 4; ++s) bQ[s] = *(const bf16x8_t*)(qp + s * 16);
    }
    bf16x8_t ones;
    #pragma unroll
    for (int e = 0; e < 8; ++e) ones[e] = (__bf16)1.0f;
    f32x16_t zro;
    #pragma unroll
    for (int e = 0; e < 16; ++e) zro[e] = 0.f;

    f32x16_t acc[2], lacc;
    #pragma unroll
    for (int e = 0; e < 16; ++e) { acc[0][e] = 0.f; acc[1][e] = 0.f; lacc[e] = 0.f; }

    auto stageK = [&](int buf, int kv0) {
        int r = tid >> 3;
        int j = (tid & 7) ^ (r & 7);
        gld_lds16(K + base + (size_t)(kv0 + r) * 64 + j * 8, &Kl[buf][wv * 64 * 8]);
    };
    auto stageV = [&](int buf, int kv0) {
        int r = tid >> 3;                      // r = d row of vt tile
        int j = (tid & 7) ^ (r & 7);
        gld_lds16(Vtg + (size_t)r * 2048 + kv0 + j * 8, &Vt[buf][wv * 64 * 8]);
    };

    const int swl = lq & 7;

    auto compute = [&](int c) {
        // QK^T both 32-key halves first (8 independent-chain MFMAs)
        f32x16_t z0, z1;
        {
            const bf16x8_t aK = *(const bf16x8_t*)&Kl[c][lq * 64 + ((hi ^ swl) * 8)];
            z0 = __builtin_amdgcn_mfma_f32_32x32x16_bf16(aK, bQ[0], zro, 0, 0, 0);
        }
        #pragma unroll
        for (int s = 1; s < 4; ++s) {
            const bf16x8_t aK = *(const bf16x8_t*)
                &Kl[c][lq * 64 + (((2 * s + hi) ^ swl) * 8)];
            z0 = __builtin_amdgcn_mfma_f32_32x32x16_bf16(aK, bQ[s], z0, 0, 0, 0);
        }
        {
            const bf16x8_t aK = *(const bf16x8_t*)&Kl[c][(32 + lq) * 64 + ((hi ^ swl) * 8)];
            z1 = __builtin_amdgcn_mfma_f32_32x32x16_bf16(aK, bQ[0], zro, 0, 0, 0);
        }
        #pragma unroll
        for (int s = 1; s < 4; ++s) {
            const bf16x8_t aK = *(const bf16x8_t*)
                &Kl[c][(32 + lq) * 64 + (((2 * s + hi) ^ swl) * 8)];
            z1 = __builtin_amdgcn_mfma_f32_32x32x16_bf16(aK, bQ[s], z1, 0, 0, 0);
        }
        // kg halves: exp/pack then PV; exp of half 1 can overlap PV of half 0
        #pragma unroll
        for (int kg = 0; kg < 2; ++kg) {
            const f32x16_t& z = kg ? z1 : z0;
            uint32_t w[4][2];
            #pragma unroll
            for (int m = 0; m < 4; ++m) {
                float p0 = __builtin_amdgcn_exp2f(z[4 * m + 0]);
                float p1 = __builtin_amdgcn_exp2f(z[4 * m + 1]);
                float p2 = __builtin_amdgcn_exp2f(z[4 * m + 2]);
                float p3 = __builtin_amdgcn_exp2f(z[4 * m + 3]);
                w[m][0] = pk2(p0, p1);
                w[m][1] = pk2(p2, p3);
            }
            #pragma unroll
            for (int sl = 0; sl < 2; ++sl) {
                const int ma = 2 * sl, sp = 2 * kg + sl;
                u32x2_t r0 = __builtin_amdgcn_permlane32_swap(w[ma][0], w[ma + 1][0], false, false);
                u32x2_t r1 = __builtin_amdgcn_permlane32_swap(w[ma][1], w[ma + 1][1], false, false);
                union { uint32_t u[4]; bf16x8_t v; } ap;
                ap.u[0] = r0[0]; ap.u[1] = r1[0]; ap.u[2] = r0[1]; ap.u[3] = r1[1];
                lacc = __builtin_amdgcn_mfma_f32_32x32x16_bf16(ap.v, ones, lacc, 0, 0, 0);
                #pragma unroll
                for (int dh = 0; dh < 2; ++dh) {
                    const bf16x8_t bV = *(const bf16x8_t*)
                        &Vt[c][(dh * 32 + lq) * 64 + (((2 * sp + hi) ^ swl) * 8)];
                    acc[dh] = __builtin_amdgcn_mfma_f32_32x32x16_bf16(ap.v, bV, acc[dh], 0, 0, 0);
                }
            }
        }
    };

    // prologue: stage tile 0
    stageK(0, 0);
    stageV(0, 0);
    __syncthreads();    // drains gld_lds (vmcnt) before reads

    for (int i = 0; i < 16; ++i) {
        const int t = 2 * i;
        stageK(1, (t + 1) * 64);           // T14: issue next-tile loads early
        stageV(1, (t + 1) * 64);
        compute(0);
        __syncthreads();
        if (t + 2 < 32) {
            stageK(0, (t + 2) * 64);
            stageV(0, (t + 2) * 64);
        }
        compute(1);
        __syncthreads();
    }

    // ---- epilogue: elementwise normalize (lacc layout == acc layout), store bf16
    f32x16_t linv;
    #pragma unroll
    for (int e = 0; e < 16; ++e) linv[e] = 1.0f / lacc[e];
    #pragma unroll
    for (int dh = 0; dh < 2; ++dh) {
        int d = dh * 32 + lq;
        #pragma unroll
        for (int e = 0; e < 16; ++e) {
            int q = q0 + (e & 3) + 8 * (e >> 2) + 4 * hi;
            ctx[((size_t)(b * 2048 + q)) * 1024 + h * 64 + d] = f2bf(acc[dh][e] * linv[e]);
        }
    }
}

// ---------- launch ----------
extern "C" void kernel_launch(void* const* d_in, const int* in_sizes, int n_in,
                              void* d_out, int out_size, void* d_ws, size_t ws_size,
                              hipStream_t stream) {
    const float* x  = (const float*)d_in[0];
    const float* Wq = (const float*)d_in[1];
    const float* Wk = (const float*)d_in[2];
    const float* Wv = (const float*)d_in[3];
    const float* Wo = (const float*)d_in[4];
    const float* bo = (const float*)d_in[5];
    float* out = (float*)d_out;

    char* ws = (char*)d_ws;
    u16* xb   = (u16*)(ws);                 // 16 MB  [8192][1024]
    u16* wT   = (u16*)(ws + 16777216);      //  8 MB  [4][1024][1024] (q,k,v,o), [out][in]
    u16* qb   = (u16*)(ws + 25165824);      // 16 MB  [64][2048][64]
    u16* kb   = (u16*)(ws + 41943040);      // 16 MB  [64][2048][64]
    u16* vtb  = (u16*)(ws + 58720256);      // 16 MB  [64][64][2048]  (V transposed)
    u16* ctx  = (u16*)(ws + 75497472);      // 16 MB  [8192][1024]

    k_convert_x<<<8192, 256, 0, stream>>>(x, xb);
    k_convert_wT<<<dim3(32, 32, 4), 256, 0, stream>>>(Wq, Wk, Wv, Wo, wT);
    k_gemm<0><<<dim3(64, 24), 256, 0, stream>>>(xb, wT, nullptr, qb, kb, vtb, nullptr);
    k_attn<<<dim3(64, 8), 512, 0, stream>>>(qb, kb, vtb, ctx);
    k_gemm<1><<<dim3(64, 8), 256, 0, stream>>>(ctx, wT, bo, nullptr, nullptr, nullptr, out);
}

// Round 13
// 171.393 us; speedup vs baseline: 4.7014x; 1.1153x over previous
//
#include <hip/hip_runtime.h>
#include <hip/hip_bf16.h>
#include <stdint.h>

typedef unsigned short u16;
typedef __bf16 bf16x8_t __attribute__((ext_vector_type(8)));
typedef float f32x4_t __attribute__((ext_vector_type(4)));
typedef float f32x16_t __attribute__((ext_vector_type(16)));
typedef unsigned int u32x2_t __attribute__((ext_vector_type(2)));

// ---------- helpers ----------
__device__ __forceinline__ u16 f2bf(float f) {
    union { float f; uint32_t u; } c; c.f = f;
    uint32_t r = c.u + 0x7FFFu + ((c.u >> 16) & 1u);
    return (u16)(r >> 16);
}

__device__ __forceinline__ uint32_t pk2(float a, float b) {
    union { __bf16 h[2]; uint32_t u; } z;
    z.h[0] = (__bf16)a; z.h[1] = (__bf16)b;
    return z.u;
}

__device__ __forceinline__ void gld_lds16(const void* g, void* l) {
    __builtin_amdgcn_global_load_lds(
        (__attribute__((address_space(1))) void*)(g),
        (__attribute__((address_space(3))) void*)(l), 16, 0, 0);
}

// Q pre-scale: 1/sqrt(64) * log2(e), so attn uses raw exp2
#define QSCALE 0.18033688011112042f

// ---------- fused conversions (one launch: x->bf16 and W^T->bf16 overlap) ----------
// blocks [0, 8192): x fp32 -> xb bf16 (float4 per thread)
// blocks [8192, 12288): transpose-convert W[in][out] fp32 -> Wt[out][in] bf16, 4 mats
__global__ void k_convert(const float* __restrict__ x, u16* __restrict__ xb,
                          const float* __restrict__ w0, const float* __restrict__ w1,
                          const float* __restrict__ w2, const float* __restrict__ w3,
                          u16* __restrict__ wT) {
    const int bx = blockIdx.x;
    if (bx < 8192) {
        int i = bx * 256 + threadIdx.x;               // 2M float4 chunks exactly
        float4 v = ((const float4*)x)[i];
        ushort4 o;
        o.x = f2bf(v.x); o.y = f2bf(v.y); o.z = f2bf(v.z); o.w = f2bf(v.w);
        ((ushort4*)xb)[i] = o;
        return;
    }
    __shared__ u16 t[32][33];
    const int w = bx - 8192;                          // [0, 4096)
    const int mat = w >> 10, rem = w & 1023;
    const float* src = (mat == 0) ? w0 : (mat == 1) ? w1 : (mat == 2) ? w2 : w3;
    u16* dst = wT + (size_t)mat * (1024 * 1024);
    int n0 = (rem & 31) * 32, k0 = (rem >> 5) * 32;
    int tx = threadIdx.x & 31, ty = threadIdx.x >> 5; // 32 x 8
    #pragma unroll
    for (int r = 0; r < 4; ++r) {
        int kl = ty * 4 + r;
        t[tx][kl] = f2bf(src[(size_t)(k0 + kl) * 1024 + n0 + tx]);
    }
    __syncthreads();
    #pragma unroll
    for (int r = 0; r < 4; ++r) {
        int nl = ty * 4 + r;
        dst[(size_t)(n0 + nl) * 1024 + k0 + tx] = t[nl][tx];
    }
}

// ---------- GEMM: C[128x128] = A[128xK] * Bt[128xK]^T, K=1024, BK=64, bf16 MFMA ----
// Single-buffered 2-barrier structure (verified optimum at this tile/shape:
// implicit cross-block overlap at 3-4 blocks/CU beats explicit dbuf at 2 — R11).
// MODE 0: A=xb, Bt=Wq/Wk/Wv^T; q scaled by QSCALE -> qo[bh][n][d];
//         k -> ko[bh][n][d]; v -> TRANSPOSED vt[bh][d][n] (ushort4 along n).
// MODE 1: A=ctx, Bt=Wo^T, write out fp32 + bias
template <int MODE>
__global__ __launch_bounds__(256, 2) void k_gemm(
    const u16* __restrict__ A, const u16* __restrict__ WT,
    const float* __restrict__ bias,
    u16* __restrict__ qo, u16* __restrict__ ko, u16* __restrict__ vt,
    float* __restrict__ out) {
    __shared__ u16 lA[128 * 64];   // 16 KB, rows of 8 16B-chunks, chunk j stored at j^(r&7)
    __shared__ u16 lB[128 * 64];
    const int tid = threadIdx.x, wv = tid >> 6, ln = tid & 63;
    const int lo = ln & 15, jg = ln >> 4;
    const int m0 = blockIdx.x * 128;
    int mat, n0;
    if (MODE == 0) { mat = blockIdx.y >> 3; n0 = (blockIdx.y & 7) * 128; }
    else           { mat = 3;               n0 = blockIdx.y * 128; }
    const u16* Bt = WT + (size_t)mat * (1024 * 1024);
    const int wm = wv >> 1, wn = wv & 1;

    f32x4_t acc[4][4];
    #pragma unroll
    for (int i = 0; i < 4; ++i)
        #pragma unroll
        for (int j = 0; j < 4; ++j) acc[i][j] = (f32x4_t){0.f, 0.f, 0.f, 0.f};

    for (int k0 = 0; k0 < 1024; k0 += 64) {
        __syncthreads();
        #pragma unroll
        for (int is = 0; is < 4; ++is) {
            int c = is * 256 + tid;
            int r = c >> 3;
            int j = (c & 7) ^ (r & 7);
            gld_lds16(A  + (size_t)(m0 + r) * 1024 + k0 + j * 8, &lA[(is * 256 + wv * 64) * 8]);
            gld_lds16(Bt + (size_t)(n0 + r) * 1024 + k0 + j * 8, &lB[(is * 256 + wv * 64) * 8]);
        }
        __syncthreads();
        #pragma unroll
        for (int sub = 0; sub < 2; ++sub) {
            bf16x8_t af[4], bfr[4];
            #pragma unroll
            for (int i = 0; i < 4; ++i) {
                int r = wm * 64 + i * 16 + lo;
                af[i] = *(const bf16x8_t*)&lA[(r * 8 + ((sub * 4 + jg) ^ (r & 7))) * 8];
            }
            #pragma unroll
            for (int j = 0; j < 4; ++j) {
                int r = wn * 64 + j * 16 + lo;
                bfr[j] = *(const bf16x8_t*)&lB[(r * 8 + ((sub * 4 + jg) ^ (r & 7))) * 8];
            }
            #pragma unroll
            for (int i = 0; i < 4; ++i)
                #pragma unroll
                for (int j = 0; j < 4; ++j)
                    acc[i][j] = __builtin_amdgcn_mfma_f32_16x16x32_bf16(af[i], bfr[j], acc[i][j], 0, 0, 0);
        }
    }

    if (MODE == 0) {
        if (mat == 2) {
            // V: transposed write vt[bh][d][n], packed ushort4 along n
            #pragma unroll
            for (int j = 0; j < 4; ++j) {
                int col = n0 + wn * 64 + j * 16 + lo;   // h*64+d
                int hh = col >> 6, dd = col & 63;
                #pragma unroll
                for (int i = 0; i < 4; ++i) {
                    int m = m0 + wm * 64 + i * 16 + jg * 4;
                    int bb = m >> 11, nn = m & 2047;
                    ushort4 pkv;
                    pkv.x = f2bf(acc[i][j][0]);
                    pkv.y = f2bf(acc[i][j][1]);
                    pkv.z = f2bf(acc[i][j][2]);
                    pkv.w = f2bf(acc[i][j][3]);
                    *(ushort4*)&vt[(((size_t)(bb * 16 + hh)) * 64 + dd) * 2048 + nn] = pkv;
                }
            }
        } else {
            u16* dst = (mat == 0) ? qo : ko;
            float sc = (mat == 0) ? QSCALE : 1.0f;
            #pragma unroll
            for (int j = 0; j < 4; ++j) {
                int col = n0 + wn * 64 + j * 16 + lo;
                int hh = col >> 6, dd = col & 63;
                #pragma unroll
                for (int i = 0; i < 4; ++i)
                    #pragma unroll
                    for (int rg = 0; rg < 4; ++rg) {
                        int m = m0 + wm * 64 + i * 16 + jg * 4 + rg;
                        int bb = m >> 11, nn = m & 2047;
                        dst[(((size_t)(bb * 16 + hh)) * 2048 + nn) * 64 + dd] = f2bf(acc[i][j][rg] * sc);
                    }
            }
        }
    } else {
        #pragma unroll
        for (int j = 0; j < 4; ++j) {
            int col = n0 + wn * 64 + j * 16 + lo;
            float bv = bias[col];
            #pragma unroll
            for (int i = 0; i < 4; ++i)
                #pragma unroll
                for (int rg = 0; rg < 4; ++rg) {
                    int m = m0 + wm * 64 + i * 16 + jg * 4 + rg;
                    out[(size_t)m * 1024 + col] = acc[i][j][rg] + bv;
                }
        }
    }
}

// ---------- flash attention, 32x32 MFMA, swapped QK^T, in-register P ----------
// (exact R6 kernel — verified 85.5 us) Block: 8 waves x 32 q = 256 q (512 thr).
// KV tiles of 64, double-buffered K/Vt in LDS via gld_lds16 (V pre-transposed).
// grid (64 bh, 8 qsplit): bh%8 -> XCD. No-max softmax (log2 domain via QSCALE).
// Row-sums via mfma(P, ones): lacc has the SAME lane layout as acc.
__global__ __launch_bounds__(512, 4) void k_attn(
    const u16* __restrict__ Q, const u16* __restrict__ K,
    const u16* __restrict__ Vg, u16* __restrict__ ctx) {
    __shared__ __align__(16) u16 Kl[2][64 * 64];   // [key][d], XOR-swizzled 16B chunks
    __shared__ __align__(16) u16 Vt[2][64 * 64];   // [d][kv], XOR-swizzled 16B chunks

    const int tid = threadIdx.x, wv = tid >> 6, ln = tid & 63;
    const int lq = ln & 31, hi = ln >> 5;
    const int bh = blockIdx.x;
    const int b = bh >> 4, h = bh & 15;
    const size_t base = (size_t)bh * 2048 * 64;    // for Q,K [bh][n][d]
    const u16* Vtg = Vg + (size_t)bh * 64 * 2048;  // vt [bh][d][n]
    const int q0 = blockIdx.y * 256 + wv * 32;

    // Q fragments (B-operand of swapped QK): lane holds Q[q=lq][d=16s+8hi..+7]
    bf16x8_t bQ[4];
    {
        const u16* qp = Q + base + (size_t)(q0 + lq) * 64 + hi * 8;
        #pragma unroll
        for (int s = 0; s < 4; ++s) bQ[s] = *(const bf16x8_t*)(qp + s * 16);
    }
    bf16x8_t ones;
    #pragma unroll
    for (int e = 0; e < 8; ++e) ones[e] = (__bf16)1.0f;
    f32x16_t zro;
    #pragma unroll
    for (int e = 0; e < 16; ++e) zro[e] = 0.f;

    f32x16_t acc[2], lacc;
    #pragma unroll
    for (int e = 0; e < 16; ++e) { acc[0][e] = 0.f; acc[1][e] = 0.f; lacc[e] = 0.f; }

    auto stageK = [&](int buf, int kv0) {
        int r = tid >> 3;
        int j = (tid & 7) ^ (r & 7);
        gld_lds16(K + base + (size_t)(kv0 + r) * 64 + j * 8, &Kl[buf][wv * 64 * 8]);
    };
    auto stageV = [&](int buf, int kv0) {
        int r = tid >> 3;                      // r = d row of vt tile
        int j = (tid & 7) ^ (r & 7);
        gld_lds16(Vtg + (size_t)r * 2048 + kv0 + j * 8, &Vt[buf][wv * 64 * 8]);
    };

    const int swl = lq & 7;

    auto compute = [&](int c) {
        // QK^T both 32-key halves first (8 independent-chain MFMAs)
        f32x16_t z0, z1;
        {
            const bf16x8_t aK = *(const bf16x8_t*)&Kl[c][lq * 64 + ((hi ^ swl) * 8)];
            z0 = __builtin_amdgcn_mfma_f32_32x32x16_bf16(aK, bQ[0], zro, 0, 0, 0);
        }
        #pragma unroll
        for (int s = 1; s < 4; ++s) {
            const bf16x8_t aK = *(const bf16x8_t*)
                &Kl[c][lq * 64 + (((2 * s + hi) ^ swl) * 8)];
            z0 = __builtin_amdgcn_mfma_f32_32x32x16_bf16(aK, bQ[s], z0, 0, 0, 0);
        }
        {
            const bf16x8_t aK = *(const bf16x8_t*)&Kl[c][(32 + lq) * 64 + ((hi ^ swl) * 8)];
            z1 = __builtin_amdgcn_mfma_f32_32x32x16_bf16(aK, bQ[0], zro, 0, 0, 0);
        }
        #pragma unroll
        for (int s = 1; s < 4; ++s) {
            const bf16x8_t aK = *(const bf16x8_t*)
                &Kl[c][(32 + lq) * 64 + (((2 * s + hi) ^ swl) * 8)];
            z1 = __builtin_amdgcn_mfma_f32_32x32x16_bf16(aK, bQ[s], z1, 0, 0, 0);
        }
        // kg halves: exp/pack then PV; exp of half 1 can overlap PV of half 0
        #pragma unroll
        for (int kg = 0; kg < 2; ++kg) {
            const f32x16_t& z = kg ? z1 : z0;
            uint32_t w[4][2];
            #pragma unroll
            for (int m = 0; m < 4; ++m) {
                float p0 = __builtin_amdgcn_exp2f(z[4 * m + 0]);
                float p1 = __builtin_amdgcn_exp2f(z[4 * m + 1]);
                float p2 = __builtin_amdgcn_exp2f(z[4 * m + 2]);
                float p3 = __builtin_amdgcn_exp2f(z[4 * m + 3]);
                w[m][0] = pk2(p0, p1);
                w[m][1] = pk2(p2, p3);
            }
            #pragma unroll
            for (int sl = 0; sl < 2; ++sl) {
                const int ma = 2 * sl, sp = 2 * kg + sl;
                u32x2_t r0 = __builtin_amdgcn_permlane32_swap(w[ma][0], w[ma + 1][0], false, false);
                u32x2_t r1 = __builtin_amdgcn_permlane32_swap(w[ma][1], w[ma + 1][1], false, false);
                union { uint32_t u[4]; bf16x8_t v; } ap;
                ap.u[0] = r0[0]; ap.u[1] = r1[0]; ap.u[2] = r0[1]; ap.u[3] = r1[1];
                lacc = __builtin_amdgcn_mfma_f32_32x32x16_bf16(ap.v, ones, lacc, 0, 0, 0);
                #pragma unroll
                for (int dh = 0; dh < 2; ++dh) {
                    const bf16x8_t bV = *(const bf16x8_t*)
                        &Vt[c][(dh * 32 + lq) * 64 + (((2 * sp + hi) ^ swl) * 8)];
                    acc[dh] = __builtin_amdgcn_mfma_f32_32x32x16_bf16(ap.v, bV, acc[dh], 0, 0, 0);
                }
            }
        }
    };

    // prologue: stage tile 0
    stageK(0, 0);
    stageV(0, 0);
    __syncthreads();    // drains gld_lds (vmcnt) before reads

    for (int i = 0; i < 16; ++i) {
        const int t = 2 * i;
        stageK(1, (t + 1) * 64);           // T14: issue next-tile loads early
        stageV(1, (t + 1) * 64);
        compute(0);
        __syncthreads();
        if (t + 2 < 32) {
            stageK(0, (t + 2) * 64);
            stageV(0, (t + 2) * 64);
        }
        compute(1);
        __syncthreads();
    }

    // ---- epilogue: elementwise normalize (lacc layout == acc layout), store bf16
    f32x16_t linv;
    #pragma unroll
    for (int e = 0; e < 16; ++e) linv[e] = 1.0f / lacc[e];
    #pragma unroll
    for (int dh = 0; dh < 2; ++dh) {
        int d = dh * 32 + lq;
        #pragma unroll
        for (int e = 0; e < 16; ++e) {
            int q = q0 + (e & 3) + 8 * (e >> 2) + 4 * hi;
            ctx[((size_t)(b * 2048 + q)) * 1024 + h * 64 + d] = f2bf(acc[dh][e] * linv[e]);
        }
    }
}

// ---------- launch ----------
extern "C" void kernel_launch(void* const* d_in, const int* in_sizes, int n_in,
                              void* d_out, int out_size, void* d_ws, size_t ws_size,
                              hipStream_t stream) {
    const float* x  = (const float*)d_in[0];
    const float* Wq = (const float*)d_in[1];
    const float* Wk = (const float*)d_in[2];
    const float* Wv = (const float*)d_in[3];
    const float* Wo = (const float*)d_in[4];
    const float* bo = (const float*)d_in[5];
    float* out = (float*)d_out;

    char* ws = (char*)d_ws;
    u16* xb   = (u16*)(ws);                 // 16 MB  [8192][1024]
    u16* wT   = (u16*)(ws + 16777216);      //  8 MB  [4][1024][1024] (q,k,v,o), [out][in]
    u16* qb   = (u16*)(ws + 25165824);      // 16 MB  [64][2048][64]
    u16* kb   = (u16*)(ws + 41943040);      // 16 MB  [64][2048][64]
    u16* vtb  = (u16*)(ws + 58720256);      // 16 MB  [64][64][2048]  (V transposed)
    u16* ctx  = (u16*)(ws + 75497472);      // 16 MB  [8192][1024]

    k_convert<<<12288, 256, 0, stream>>>(x, xb, Wq, Wk, Wv, Wo, wT);
    k_gemm<0><<<dim3(64, 24), 256, 0, stream>>>(xb, wT, nullptr, qb, kb, vtb, nullptr);
    k_attn<<<dim3(64, 8), 512, 0, stream>>>(qb, kb, vtb, ctx);
    k_gemm<1><<<dim3(64, 8), 256, 0, stream>>>(ctx, wT, bo, nullptr, nullptr, nullptr, out);
}